// Round 2
// baseline (33.584 us; speedup 1.0000x reference)
//
#include <hip/hip_runtime.h>

#define BATCH 4096
#define NCLS  1024
#define DEPTH 10
#define NBLOCKS (BATCH / 4)   // 1024 blocks, 4 waves (samples) per block

// Fused kernel: per-sample hierarchical loss + grid-wide mean via
// partials + atomic counter + last-block final reduction (deterministic:
// the final reduction reads partials in a fixed order).
//
// Per wave (64 lanes), one sample. Lane l holds row elements [l*16, l*16+16).
// Aligned block sums along target t's root path:
//   S[0..4]  : within the owning lane's 16-element segment (t is wave-uniform
//              so the selects are uniform; only lane t>>4 has the real path).
//   S[5..10] : __shfl_xor butterfly; after step k each lane holds the sum of
//              its aligned 2^(k+1)-lane group.
__global__ __launch_bounds__(256) void hll_fused(
    const float* __restrict__ inputs,
    const int*   __restrict__ target,
    const float* __restrict__ weights,
    float*       __restrict__ partials,
    unsigned int* __restrict__ counter,
    float*       __restrict__ out)
{
    const int wave = threadIdx.x >> 6;
    const int lane = threadIdx.x & 63;
    const int b = blockIdx.x * 4 + wave;

    const int t = target[b];                       // wave-uniform
    const float4* row = reinterpret_cast<const float4*>(inputs + (size_t)b * NCLS);

    float4 x0 = row[lane * 4 + 0];
    float4 x1 = row[lane * 4 + 1];
    float4 x2 = row[lane * 4 + 2];
    float4 x3 = row[lane * 4 + 3];

    const int s = t & 15;
    const int q = s >> 2;
    const int r = s & 3;

    float4 xq = (q == 0) ? x0 : (q == 1) ? x1 : (q == 2) ? x2 : x3;

    float S[DEPTH + 1];
    S[0] = (r == 0) ? xq.x : (r == 1) ? xq.y : (r == 2) ? xq.z : xq.w;
    S[1] = (r < 2) ? (xq.x + xq.y) : (xq.z + xq.w);
    S[2] = xq.x + xq.y + xq.z + xq.w;

    const float q0 = x0.x + x0.y + x0.z + x0.w;
    const float q1 = x1.x + x1.y + x1.z + x1.w;
    const float q2 = x2.x + x2.y + x2.z + x2.w;
    const float q3 = x3.x + x3.y + x3.z + x3.w;
    S[3] = (q < 2) ? (q0 + q1) : (q2 + q3);
    S[4] = q0 + q1 + q2 + q3;

    float ssum = S[4];
    #pragma unroll
    for (int k = 0; k < 6; ++k) {
        ssum += __shfl_xor(ssum, 1 << k, 64);
        S[5 + k] = ssum;
    }

    const float* w = weights + (size_t)t * DEPTH;

    float acc = 0.0f;
    #pragma unroll
    for (int j = 0; j < DEPTH; ++j) {
        const float num = S[j];
        const float den = S[j + 1];
        const float val = (num != 0.0f) ? -__logf(num / den) : num;
        acc += w[j] * val;
    }

    // broadcast the owner lane's loss to the whole wave
    const float loss = __shfl(acc, t >> 4, 64);

    __shared__ float wsum[4];
    __shared__ int   is_last;
    if (lane == 0) wsum[wave] = loss;
    __syncthreads();

    if (threadIdx.x == 0) {
        partials[blockIdx.x] = wsum[0] + wsum[1] + wsum[2] + wsum[3];
        __threadfence();                       // make partial visible device-wide
        unsigned int old = atomicAdd(counter, 1u);
        is_last = (old == NBLOCKS - 1);
    }
    __syncthreads();

    if (is_last) {
        __threadfence();                       // acquire: see all partials
        const int tid = threadIdx.x;
        float sum = 0.0f;
        #pragma unroll
        for (int i = 0; i < NBLOCKS / 256; ++i)
            sum += ((volatile const float*)partials)[tid + i * 256];
        __shared__ float lds[256];
        lds[tid] = sum;
        __syncthreads();
        #pragma unroll
        for (int off = 128; off > 0; off >>= 1) {
            if (tid < off) lds[tid] += lds[tid + off];
            __syncthreads();
        }
        if (tid == 0) out[0] = lds[0] * (1.0f / (float)BATCH);
    }
}

extern "C" void kernel_launch(void* const* d_in, const int* in_sizes, int n_in,
                              void* d_out, int out_size, void* d_ws, size_t ws_size,
                              hipStream_t stream) {
    const float* inputs  = (const float*)d_in[0];
    const int*   target  = (const int*)d_in[1];
    // d_in[2] = onehot_num, d_in[3] = onehot_den: structural, not needed.
    const float* weights = (const float*)d_in[4];

    float*        partials = (float*)d_ws;                       // NBLOCKS floats
    unsigned int* counter  = (unsigned int*)((char*)d_ws + 8192); // 4 bytes, aligned
    float*        out      = (float*)d_out;

    // counter must start at 0 every call (ws is poisoned once, never restored)
    hipMemsetAsync(counter, 0, sizeof(unsigned int), stream);

    hll_fused<<<NBLOCKS, 256, 0, stream>>>(inputs, target, weights,
                                           partials, counter, out);
}

// Round 3
// 11.151 us; speedup vs baseline: 3.0119x; 3.0119x over previous
//
#include <hip/hip_runtime.h>

#define BATCH 4096
#define NCLS  1024
#define DEPTH 10
#define NBLOCKS (BATCH / 4)   // 1024 blocks, 4 waves (one sample each) per block

// Kernel 1: per-sample hierarchical loss, block-reduced to one partial/block.
//
// Per wave (64 lanes), one sample. Lane l holds row elements [l*16, l*16+16).
// Aligned block sums along target t's root path:
//   S[0..4]  : within the owning lane's 16-element segment (t is wave-uniform
//              so the selects are uniform; only lane t>>4 has the real path).
//   S[5..10] : __shfl_xor butterfly; after step k each lane holds the sum of
//              its aligned 2^(k+1)-lane group — lane t>>4 carries the true path.
__global__ __launch_bounds__(256) void hll_per_block(
    const float* __restrict__ inputs,
    const int*   __restrict__ target,
    const float* __restrict__ weights,
    float*       __restrict__ partials)
{
    const int wave = threadIdx.x >> 6;
    const int lane = threadIdx.x & 63;
    const int b = blockIdx.x * 4 + wave;

    const int t = target[b];                       // wave-uniform
    const float4* row = reinterpret_cast<const float4*>(inputs + (size_t)b * NCLS);

    float4 x0 = row[lane * 4 + 0];
    float4 x1 = row[lane * 4 + 1];
    float4 x2 = row[lane * 4 + 2];
    float4 x3 = row[lane * 4 + 3];

    const int s = t & 15;
    const int q = s >> 2;
    const int r = s & 3;

    float4 xq = (q == 0) ? x0 : (q == 1) ? x1 : (q == 2) ? x2 : x3;

    float S[DEPTH + 1];
    S[0] = (r == 0) ? xq.x : (r == 1) ? xq.y : (r == 2) ? xq.z : xq.w;
    S[1] = (r < 2) ? (xq.x + xq.y) : (xq.z + xq.w);
    S[2] = xq.x + xq.y + xq.z + xq.w;

    const float q0 = x0.x + x0.y + x0.z + x0.w;
    const float q1 = x1.x + x1.y + x1.z + x1.w;
    const float q2 = x2.x + x2.y + x2.z + x2.w;
    const float q3 = x3.x + x3.y + x3.z + x3.w;
    S[3] = (q < 2) ? (q0 + q1) : (q2 + q3);
    S[4] = q0 + q1 + q2 + q3;

    float ssum = S[4];
    #pragma unroll
    for (int k = 0; k < 6; ++k) {
        ssum += __shfl_xor(ssum, 1 << k, 64);
        S[5 + k] = ssum;
    }

    const float* w = weights + (size_t)t * DEPTH;

    float acc = 0.0f;
    #pragma unroll
    for (int j = 0; j < DEPTH; ++j) {
        const float num = S[j];
        const float den = S[j + 1];
        const float val = (num != 0.0f) ? -__logf(num / den) : num;
        acc += w[j] * val;
    }

    // loss for this sample lives in lane t>>4; reduce 4 waves' losses in LDS
    __shared__ float wsum[4];
    if (lane == (t >> 4)) wsum[wave] = acc;
    __syncthreads();
    if (threadIdx.x == 0)
        partials[blockIdx.x] = wsum[0] + wsum[1] + wsum[2] + wsum[3];
}

// Kernel 2: single-wave deterministic mean over the 1024 block partials.
__global__ __launch_bounds__(64) void hll_reduce(
    const float* __restrict__ partials,
    float*       __restrict__ out)
{
    const int lane = threadIdx.x;
    const float4* p4 = reinterpret_cast<const float4*>(partials);
    float s = 0.0f;
    #pragma unroll
    for (int i = 0; i < NBLOCKS / 256; ++i) {   // 4 × float4 per lane
        float4 v = p4[lane + i * 64];
        s += v.x + v.y + v.z + v.w;
    }
    #pragma unroll
    for (int k = 0; k < 6; ++k)
        s += __shfl_xor(s, 1 << k, 64);
    if (lane == 0) out[0] = s * (1.0f / (float)BATCH);
}

extern "C" void kernel_launch(void* const* d_in, const int* in_sizes, int n_in,
                              void* d_out, int out_size, void* d_ws, size_t ws_size,
                              hipStream_t stream) {
    const float* inputs  = (const float*)d_in[0];
    const int*   target  = (const int*)d_in[1];
    // d_in[2] = onehot_num, d_in[3] = onehot_den: structural, not needed.
    const float* weights = (const float*)d_in[4];

    float* partials = (float*)d_ws;   // NBLOCKS floats, fully rewritten each call
    float* out      = (float*)d_out;

    hll_per_block<<<NBLOCKS, 256, 0, stream>>>(inputs, target, weights, partials);
    hll_reduce<<<1, 64, 0, stream>>>(partials, out);
}